// Round 14
// baseline (69.549 us; speedup 1.0000x reference)
//
#include <hip/hip_runtime.h>

#define SS 4096
#define DD 1024
#define EE 128
#define SCALE 0.08838834764831845f   // 1/sqrt(128)

typedef __bf16 bf16x8 __attribute__((ext_vector_type(8)));
typedef float  f32x4  __attribute__((ext_vector_type(4)));

// ---------------------------------------------------------------------------
// K1: fused QKV projection.  BM=128 BN=128(=E) BK=64; grid 192 = 64 rt x 3 ct
// (ct0=Q, ct1=K, ct2=V — no column routing).  256 thr, 4 waves (2x2), wave
// tile 64x64 (acc 4x4): 16 LDS reads / 32 MFMA per wave-step (0.5 ratio, half
// of all prior rounds — LDS-BW was the invariant bottleneck).
// A and B reg-staged fp32 -> cvt -> XOR-swizzled bf16 ds_write (T14: loads
// before COMPUTE, writes after).  LDS 64 KB.  XCD swizzle ct-fastest.
// ---------------------------------------------------------------------------
__global__ __launch_bounds__(256) void proj_kernel(
    const float* __restrict__ x,
    const float* __restrict__ qW, const float* __restrict__ qB,
    const float* __restrict__ kW, const float* __restrict__ kB,
    const float* __restrict__ vW, const float* __restrict__ vB,
    __bf16* __restrict__ Qbf, __bf16* __restrict__ KT, __bf16* __restrict__ VT)
{
  __shared__ __attribute__((aligned(16))) __bf16 ldsA[2][128 * 64];  // 32 KB
  __shared__ __attribute__((aligned(16))) __bf16 ldsB[2][128 * 64];  // 32 KB

  const int tid  = threadIdx.x;
  const int w    = tid >> 6, lane = tid & 63;
  const int l15  = lane & 15, l4 = lane >> 4;
  const int wr   = w >> 1, wc = w & 1;          // wave tile 64r x 64c

  // XCD swizzle (192 % 8 == 0): same-XCD blocks are ct-fastest -> the 3
  // ctiles sharing an x rtile run consecutively on one XCD's L2.
  const int id   = blockIdx.x;
  const int swz  = (id & 7) * 24 + (id >> 3);
  const int rt   = swz / 3, ct = swz % 3;       // rt 0..63, ct 0..2
  const int row0 = rt * 128;                    // flat row [0,8192)

  const float* __restrict__ Wsel = (ct == 0) ? qW : (ct == 1 ? kW : vW);
  const float* __restrict__ bias = (ct == 0) ? qB : (ct == 1 ? kB : vB);

  // reg-staging geometry (A and B identical): thread -> (row=tid>>1, half)
  const int srow = tid >> 1;                    // 0..127
  const int sseg = tid & 1;                     // 32 floats at k = sseg*32
  const int srs  = srow & 7;
  const float* gA = x    + (size_t)(row0 + srow) * DD + sseg * 32;
  const float* gB = Wsel + (size_t)srow * DD + sseg * 32;

  f32x4 acc[4][4] = {};
  f32x4 rA[8], rB[8];

#define LOADS(T) {                                                           \
    const float* ga_ = gA + (T) * 64;                                        \
    const float* gb_ = gB + (T) * 64;                                        \
    _Pragma("unroll") for (int q = 0; q < 8; ++q) {                          \
      rA[q] = *(const f32x4*)(ga_ + q * 4);                                  \
      rB[q] = *(const f32x4*)(gb_ + q * 4);                                  \
    } }

#define WRITES(P) {                                                          \
    _Pragma("unroll") for (int qq = 0; qq < 4; ++qq) {                       \
      bf16x8 va_ = { (__bf16)rA[2*qq][0], (__bf16)rA[2*qq][1],               \
                     (__bf16)rA[2*qq][2], (__bf16)rA[2*qq][3],               \
                     (__bf16)rA[2*qq+1][0], (__bf16)rA[2*qq+1][1],           \
                     (__bf16)rA[2*qq+1][2], (__bf16)rA[2*qq+1][3] };         \
      bf16x8 vb_ = { (__bf16)rB[2*qq][0], (__bf16)rB[2*qq][1],               \
                     (__bf16)rB[2*qq][2], (__bf16)rB[2*qq][3],               \
                     (__bf16)rB[2*qq+1][0], (__bf16)rB[2*qq+1][1],           \
                     (__bf16)rB[2*qq+1][2], (__bf16)rB[2*qq+1][3] };         \
      const int ch_ = (sseg * 4 + qq) ^ srs;                                 \
      *(bf16x8*)&ldsA[P][srow * 64 + (ch_ << 3)] = va_;                      \
      *(bf16x8*)&ldsB[P][srow * 64 + (ch_ << 3)] = vb_;                      \
    } }

#define COMPUTE(P) {                                                         \
    const int rs7 = l15 & 7;                                                 \
    _Pragma("unroll") for (int ks = 0; ks < 2; ++ks) {                       \
      const int so = ((ks * 4 + l4) ^ rs7) << 3;                             \
      bf16x8 af[4], bq[4];                                                   \
      _Pragma("unroll") for (int m = 0; m < 4; ++m)                          \
        af[m] = *(const bf16x8*)&ldsA[P][(wr * 64 + m * 16 + l15) * 64 + so];\
      _Pragma("unroll") for (int n = 0; n < 4; ++n)                          \
        bq[n] = *(const bf16x8*)&ldsB[P][(wc * 64 + n * 16 + l15) * 64 + so];\
      _Pragma("unroll") for (int m = 0; m < 4; ++m)                          \
        _Pragma("unroll") for (int n = 0; n < 4; ++n)                        \
          acc[m][n] = __builtin_amdgcn_mfma_f32_16x16x32_bf16(               \
              af[m], bq[n], acc[m][n], 0, 0, 0);                             \
    } }

  // prologue: stage tile 0
  LOADS(0);
  WRITES(0);
  __syncthreads();
  for (int t = 0; t < 16; ++t) {
    const int P = t & 1;
    if (t < 15) LOADS(t + 1);          // issue early (T14)
    COMPUTE(P);                        // hides global latency
    if (t < 15) WRITES(P ^ 1);         // cvt+write late
    __syncthreads();
  }
#undef LOADS
#undef WRITES
#undef COMPUTE

  if (ct == 0) {                                 // Q: row-major, *SCALE folded
    #pragma unroll
    for (int m = 0; m < 4; ++m)
      #pragma unroll
      for (int n = 0; n < 4; ++n) {
        const int col = wc * 64 + n * 16 + l15;
        const float bv = bias[col];
        #pragma unroll
        for (int r = 0; r < 4; ++r) {
          const int row = row0 + wr * 64 + m * 16 + l4 * 4 + r;
          Qbf[(size_t)row * EE + col] =
              (__bf16)((acc[m][n][r] + bv) * SCALE);
        }
      }
  } else {                                       // K/V: transpose via LDS
    __bf16* Tb = (__bf16*)ldsA;                  // [128 cols][128 rows] 32 KB
    #pragma unroll
    for (int m = 0; m < 4; ++m)
      #pragma unroll
      for (int n = 0; n < 4; ++n) {
        const int tc = wc * 64 + n * 16 + l15;   // output col e/f
        const float bv = bias[tc];
        #pragma unroll
        for (int r = 0; r < 4; ++r) {
          const int rl = wr * 64 + m * 16 + l4 * 4 + r;   // s-row 0..127
          Tb[tc * 128 + (((rl >> 3) ^ (tc & 7)) << 3) + (rl & 7)] =
              (__bf16)(acc[m][n][r] + bv);
        }
      }
    __syncthreads();
    const int col = tid >> 1, p2 = tid & 1;      // 128 cols x 2 thr
    const int b = row0 >> 12, s0 = row0 & 4095;
    __bf16* dst = ((ct == 1) ? KT : VT) + ((size_t)b * EE + col) * SS + s0;
    #pragma unroll
    for (int j = 0; j < 8; ++j) {
      const int ch = p2 * 8 + j;                 // 16 chunks of 8 bf16
      bf16x8 v = *(const bf16x8*)&Tb[col * 128 + ((ch ^ (col & 7)) << 3)];
      *(bf16x8*)&dst[ch * 8] = v;
    }
  }
}

// ---------------------------------------------------------------------------
// K2: partial K^T V.  grid (64 s-chunks, 2 f-halves, 2 b) x 256 thr.
// ---------------------------------------------------------------------------
__global__ __launch_bounds__(256) void ktv_kernel(
    const __bf16* __restrict__ KT, const __bf16* __restrict__ VT,
    float* __restrict__ part)
{
  const int c = blockIdx.x, fh = blockIdx.y, b = blockIdx.z;
  const int tid = threadIdx.x;
  const int w = tid >> 6, lane = tid & 63;
  const int l15 = lane & 15, l4 = lane >> 4;
  const int s0 = c * 64;
  const int fbase = fh * 64 + w * 16;
  const __bf16* Kb = KT + (size_t)b * EE * SS;
  const __bf16* Vb = VT + (size_t)b * EE * SS;

  f32x4 acc[8] = {};
  #pragma unroll
  for (int ks = 0; ks < 2; ++ks) {
    const int s = s0 + ks * 32 + 8 * l4;
    bf16x8 bv = *(const bf16x8*)&Vb[(size_t)(fbase + l15) * SS + s];
    #pragma unroll
    for (int i = 0; i < 8; ++i) {
      bf16x8 av = *(const bf16x8*)&Kb[(size_t)(i * 16 + l15) * SS + s];
      acc[i] = __builtin_amdgcn_mfma_f32_16x16x32_bf16(av, bv, acc[i], 0, 0, 0);
    }
  }
  float* P = part + (size_t)(b * 64 + c) * 16384;
  #pragma unroll
  for (int i = 0; i < 8; ++i)
    #pragma unroll
    for (int r = 0; r < 4; ++r) {
      int e = i * 16 + l4 * 4 + r;
      int f = fbase + l15;
      P[e * 128 + f] = acc[i][r];
    }
}

// ---------------------------------------------------------------------------
// K3: reduce 64 partials -> MT[b][f][e] = sum (scale folded into Qbf).
// ---------------------------------------------------------------------------
__global__ __launch_bounds__(256) void reduce_kernel(
    const float* __restrict__ part, __bf16* __restrict__ MT)
{
  const int b = blockIdx.y;
  const int e = blockIdx.x * 2 + (threadIdx.x >> 7);
  const int f = threadIdx.x & 127;
  float s = 0.f;
  for (int cc = 0; cc < 64; ++cc)
    s += part[(size_t)(b * 64 + cc) * 16384 + e * 128 + f];
  MT[((size_t)b * EE + f) * EE + e] = (__bf16)s;
}

// ---------------------------------------------------------------------------
// K4: O = Q * M  (MT[f][e]).  grid (128, 2) x 128 thr.
// ---------------------------------------------------------------------------
__global__ __launch_bounds__(128) void qm_kernel(
    const __bf16* __restrict__ Qbf, const __bf16* __restrict__ MT,
    float* __restrict__ out)
{
  const int b = blockIdx.y;
  const int tid = threadIdx.x;
  const int w = tid >> 6, lane = tid & 63;
  const int l15 = lane & 15, l4 = lane >> 4;
  const int row0 = blockIdx.x * 32 + w * 16;
  const __bf16* Qb = Qbf + (size_t)b * SS * EE;
  const __bf16* Mb = MT + (size_t)b * EE * EE;

  f32x4 acc[8] = {};
  #pragma unroll
  for (int ks = 0; ks < 4; ++ks) {
    const int e = ks * 32 + 8 * l4;
    bf16x8 av = *(const bf16x8*)&Qb[(size_t)(row0 + l15) * EE + e];
    #pragma unroll
    for (int j = 0; j < 8; ++j) {
      bf16x8 bv = *(const bf16x8*)&Mb[(size_t)(j * 16 + l15) * EE + e];
      acc[j] = __builtin_amdgcn_mfma_f32_16x16x32_bf16(av, bv, acc[j], 0, 0, 0);
    }
  }
  #pragma unroll
  for (int j = 0; j < 8; ++j)
    #pragma unroll
    for (int r = 0; r < 4; ++r) {
      int srow = row0 + l4 * 4 + r;
      int f = j * 16 + l15;
      out[((size_t)b * SS + srow) * EE + f] = acc[j][r];
    }
}

extern "C" void kernel_launch(void* const* d_in, const int* in_sizes, int n_in,
                              void* d_out, int out_size, void* d_ws, size_t ws_size,
                              hipStream_t stream) {
  const float* x  = (const float*)d_in[0];
  const float* qW = (const float*)d_in[1];
  const float* qB = (const float*)d_in[2];
  const float* kW = (const float*)d_in[3];
  const float* kB = (const float*)d_in[4];
  const float* vW = (const float*)d_in[5];
  const float* vB = (const float*)d_in[6];
  float* out = (float*)d_out;

  char* base = (char*)d_ws;
  __bf16* Qbf = (__bf16*)(base);                         // 2 MB
  __bf16* KT  = (__bf16*)(base + (2u  << 20));           // 2 MB
  __bf16* VT  = (__bf16*)(base + (4u  << 20));           // 2 MB
  float*  part= (float*) (base + (6u  << 20));           // 8 MB
  __bf16* MT  = (__bf16*)(base + (14u << 20));           // 64 KB

  proj_kernel  <<<dim3(192),      256, 0, stream>>>(x, qW, qB, kW, kB, vW, vB,
                                                    Qbf, KT, VT);
  ktv_kernel   <<<dim3(64, 2, 2), 256, 0, stream>>>(KT, VT, part);
  reduce_kernel<<<dim3(64, 2),    256, 0, stream>>>(part, MT);
  qm_kernel    <<<dim3(128, 2),   128, 0, stream>>>(Qbf, MT, out);
}